// Round 10
// baseline (143.759 us; speedup 1.0000x reference)
//
#include <hip/hip_runtime.h>
#include <math.h>

typedef _Float16 half8 __attribute__((ext_vector_type(8)));
typedef _Float16 half4h __attribute__((ext_vector_type(4)));
typedef float floatx4 __attribute__((ext_vector_type(4)));

#define HDIM 256
#define NC 15        // value + 4 grad + 10 hess
#define NCP 16       // comps padded to 16 (comp 15 = always zero)
#define SPB 4        // samples per block
#define MR 64        // M rows = NCP * SPB
#define NWAVE 4
#define NT 4         // n-tiles per wave (64 neurons)

// Row map: m = 16*(c>>2) + 4*sl + (c&3)  (mt = c>>2, row_in_tile = 4*sl+(c&3)).
// MFMA C/D: row = 4q+r -> lane (col,q) holds comp c=4mt+r of sample sl=q:
// ALL 16 comps of ONE sample per lane -> chain rule register-local.
// LDS: st[64][256] f16 = 32768 B; 8-f16-chunk XOR swizzle phys = c8 ^ (m&31).
// Budget (R6-R9 lesson): 512 regs/SIMD pool. SPB=4 -> acc=64/thread, so
// __launch_bounds__(256,3) = 3 blocks/CU, ~170 regs/wave = 64 AGPR + ~106
// arch: every phase fits, no scratch. Einstein tail: NO address-taken arrays
// (R8/R9: Gf/Hs/res call-site arrays -> 27 MB scratch traffic).

// ---------------------------------------------------------------------------
// Coalesced 64x64 LDS-tile transpose: Wt[m][j*256+k] = (f16)W_m[k*256+j].
// ---------------------------------------------------------------------------
__global__ __launch_bounds__(1024) void pack_wt(
    const float* __restrict__ W2, const float* __restrict__ W3,
    _Float16* __restrict__ Wt)
{
    __shared__ float t[64][65];
    const int m    = blockIdx.x >> 4;
    const float* W = m ? W3 : W2;
    const int tile = blockIdx.x & 15;
    const int k0 = (tile >> 2) * 64, j0 = (tile & 3) * 64;
    const int tx = threadIdx.x & 63, ty = threadIdx.x >> 6;   // 64 x 16
#pragma unroll
    for (int i = 0; i < 4; ++i) {
        int k = ty + i * 16;
        t[k][tx] = W[(k0 + k) * HDIM + j0 + tx];
    }
    __syncthreads();
#pragma unroll
    for (int i = 0; i < 4; ++i) {
        int jj = ty + i * 16;
        Wt[(size_t)m * HDIM * HDIM + (j0 + jj) * HDIM + k0 + tx] =
            (_Float16)t[tx][jj];
    }
}

// ---------------------------------------------------------------------------
// Fused kernel: MFMA forward-mode (value,grad,hess) + parallel Einstein tail.
// ---------------------------------------------------------------------------
template <bool TW>
__global__ __launch_bounds__(256, 3) void mlp_fused(
    const float* __restrict__ coords,
    const float* __restrict__ W1, const float* __restrict__ b1,
    const float* __restrict__ W2, const float* __restrict__ b2,
    const float* __restrict__ W3, const float* __restrict__ b3,
    const float* __restrict__ Wo, const float* __restrict__ bo,
    const _Float16* __restrict__ Wt,   // packed f16 W2^T | W3^T (TW only)
    float* __restrict__ out, int B)
{
    __shared__ __align__(16) _Float16 st[MR * HDIM];   // 32,768 B

    const int tid  = threadIdx.x;
    const int w    = tid >> 6;       // wave 0..3
    const int lane = tid & 63;
    const int col  = lane & 15;
    const int q    = lane >> 4;      // = sample-local index in C/D
    const int s0   = blockIdx.x * SPB;

    floatx4 acc[4][NT];              // 64 unified regs (AGPR)

    auto f4get = [](const float4& v, int i) -> float {
        switch (i & 3) { case 0: return v.x; case 1: return v.y;
                         case 2: return v.z; default: return v.w; }
    };

    // ---- layer-1 producer: thread = (sample tid&3, 4-col chunk tid>>2) ----
    auto produce1 = [&]() {
        const int sl = tid & 3;
        const int tc = tid >> 2;               // 0..63
        int ss = s0 + sl; if (ss >= B) ss = B - 1;
        const float x0 = coords[ss * 4 + 0];
        const float x1 = coords[ss * 4 + 1];
        const float x2 = coords[ss * 4 + 2];
        const float x3 = coords[ss * 4 + 3];
        const int jg = tc * 4;
        float4 wa0 = *(const float4*)&W1[0 * HDIM + jg];
        float4 wa1 = *(const float4*)&W1[1 * HDIM + jg];
        float4 wa2 = *(const float4*)&W1[2 * HDIM + jg];
        float4 wa3 = *(const float4*)&W1[3 * HDIM + jg];
        float4 bb  = *(const float4*)&b1[jg];
        half4h ch4[NCP];                       // constant-indexed -> regs
#pragma unroll
        for (int jj = 0; jj < 4; ++jj) ch4[15][jj] = (_Float16)0.f;
#pragma unroll
        for (int jj = 0; jj < 4; ++jj) {
            float w0 = f4get(wa0, jj), w1 = f4get(wa1, jj);
            float w2v = f4get(wa2, jj), w3v = f4get(wa3, jj);
            float a = f4get(bb, jj);
            a = fmaf(x0, w0, a); a = fmaf(x1, w1, a);
            a = fmaf(x2, w2v, a); a = fmaf(x3, w3v, a);
            float v = tanhf(a), tp = 1.f - v * v, m2 = -2.f * v * tp;
            float g[4] = {w0, w1, w2v, w3v};
            ch4[0][jj] = (_Float16)v;
#pragma unroll
            for (int k = 0; k < 4; ++k) ch4[1 + k][jj] = (_Float16)(tp * g[k]);
            int idx = 5;
#pragma unroll
            for (int aa = 0; aa < 4; ++aa)
#pragma unroll
                for (int bb2 = aa; bb2 < 4; ++bb2) {
                    ch4[idx][jj] = (_Float16)(m2 * g[aa] * g[bb2]); ++idx;
                }
        }
        const int c8 = tc >> 1, o4 = (tc & 1) * 4;
#pragma unroll
        for (int c = 0; c < NCP; ++c) {
            const int m = 16 * (c >> 2) + 4 * sl + (c & 3);
            *(half4h*)&st[m * HDIM + (((c8 ^ m) & 31) << 3) + o4] = ch4[c];
        }
    };

    auto init_acc = [&](const float* __restrict__ b) {
#pragma unroll
        for (int nt = 0; nt < NT; ++nt) {
            float bj = b[w * 64 + nt * 16 + col];
#pragma unroll
            for (int mt = 0; mt < 4; ++mt)
#pragma unroll
                for (int r = 0; r < 4; ++r) acc[mt][nt][r] = 0.f;
            acc[0][nt][0] = bj;                // comp 0 (mt=0, r=0)
        }
    };

    // full-K GEMM: A = st (swizzled LDS), B = Wt rows (f16, k-contiguous)
    auto gemm_full = [&](const float* __restrict__ W, int layer) {
#pragma unroll
        for (int ks = 0; ks < 8; ++ks) {
            const int kg = ks * 32 + q * 8;
            half8 bf[NT];
#pragma unroll
            for (int nt = 0; nt < NT; ++nt) {
                const int j = w * 64 + nt * 16 + col;
                if constexpr (TW) {
                    bf[nt] = *(const half8*)&Wt[((size_t)layer * HDIM + j) * HDIM + kg];
                } else {
#pragma unroll
                    for (int i = 0; i < 8; ++i)
                        bf[nt][i] = (_Float16)W[(kg + i) * HDIM + j];
                }
            }
            const int lc = ks * 4 + q;         // logical chunk
#pragma unroll
            for (int mt = 0; mt < 4; ++mt) {
                const int m = 16 * mt + col;
                half8 af = *(const half8*)&st[m * HDIM + (((lc ^ m) & 31) << 3)];
#pragma unroll
                for (int nt = 0; nt < NT; ++nt)
                    acc[mt][nt] = __builtin_amdgcn_mfma_f32_16x16x32_f16(
                        af, bf[nt], acc[mt][nt], 0, 0, 0);
            }
        }
    };

    // tanh chain rule + immediate LDS store (lane-local; c = 4*mt + r)
    auto transform_store = [&]() {
#pragma unroll
        for (int nt = 0; nt < NT; ++nt) {
            const int j = w * 64 + nt * 16 + col;
            const int jc = j >> 3, jb = j & 7;
            float pre[NCP];
#pragma unroll
            for (int c = 0; c < NCP; ++c) pre[c] = acc[c >> 2][nt][c & 3];
            float v = tanhf(pre[0]), tp = 1.f - v * v, m2 = -2.f * v * tp;
            float g[4] = {pre[1], pre[2], pre[3], pre[4]};
            float ns[NCP];
            ns[0] = v;
#pragma unroll
            for (int k = 0; k < 4; ++k) ns[1 + k] = tp * g[k];
            int idx = 5;
#pragma unroll
            for (int aa = 0; aa < 4; ++aa)
#pragma unroll
                for (int bb2 = aa; bb2 < 4; ++bb2) {
                    ns[idx] = fmaf(tp, pre[idx], m2 * g[aa] * g[bb2]); ++idx;
                }
            ns[15] = 0.f;
#pragma unroll
            for (int c = 0; c < NCP; ++c) {
                const int m = 16 * (c >> 2) + 4 * q + (c & 3);
                st[m * HDIM + (((jc ^ m) & 31) << 3) + jb] = (_Float16)ns[c];
            }
        }
    };

    // ================= pipeline =================
    produce1();
    __syncthreads();
    init_acc(b2);
    gemm_full(W2, 0);
    __syncthreads();                  // layer-1 state consumed
    transform_store();                // layer-2 state -> st
    __syncthreads();
    init_acc(b3);
    gemm_full(W3, 1);

    // ---- epilogue: layer-3 tanh chain + Wo dot (lane = sample q) ----
    __syncthreads();                  // st consumed; alias for partials
    float* part = (float*)st;         // [0, 240): part[w][sl][c]
    float* fin  = ((float*)st) + 256; // [256, 320): fin[sl][16]
    {
        float on[NC];
#pragma unroll
        for (int c = 0; c < NC; ++c) on[c] = 0.f;
#pragma unroll
        for (int nt = 0; nt < NT; ++nt) {
            const float wo = Wo[w * 64 + nt * 16 + col];
            float pre[NCP];
#pragma unroll
            for (int c = 0; c < NCP; ++c) pre[c] = acc[c >> 2][nt][c & 3];
            float v = tanhf(pre[0]), tp = 1.f - v * v, m2 = -2.f * v * tp;
            float g[4] = {pre[1], pre[2], pre[3], pre[4]};
            on[0] = fmaf(wo, v, on[0]);
#pragma unroll
            for (int k = 0; k < 4; ++k) on[1 + k] = fmaf(wo, tp * g[k], on[1 + k]);
            int idx = 5;
#pragma unroll
            for (int aa = 0; aa < 4; ++aa)
#pragma unroll
                for (int bb2 = aa; bb2 < 4; ++bb2) {
                    on[idx] = fmaf(wo, fmaf(tp, pre[idx], m2 * g[aa] * g[bb2]),
                                   on[idx]);
                    ++idx;
                }
        }
#pragma unroll
        for (int mask = 1; mask < 16; mask <<= 1)
#pragma unroll
            for (int c = 0; c < NC; ++c)
                on[c] += __shfl_xor(on[c], mask, 64);
        if (col == 0) {
#pragma unroll
            for (int c = 0; c < NC; ++c)
                part[(w * SPB + q) * NC + c] = on[c];
        }
    }
    __syncthreads();
    if (tid < SPB * NC) {             // 60 threads
        const int sl = tid / NC, c = tid % NC;
        float v = 0.f;
#pragma unroll
        for (int ww = 0; ww < NWAVE; ++ww) v += part[(ww * SPB + sl) * NC + c];
        if (c == 0) v += bo[0];
        fin[sl * 16 + c] = v;
    }
    __syncthreads();

    // ---- Einstein tail: wave 0, lane = (sample sq, component e=(i,j)) ----
    // Fully scalar (select chains on runtime i,j; sums over a,e unrolled).
    if (tid < 64) {
        const int sq = tid >> 4;             // 0..3
        const int e  = tid & 15;
        const int io = e >> 2, jo = e & 3;   // output indices (i,j)
        const int s  = s0 + sq;
        if (s < B) {
            const float f  = fin[sq * 16 + 0];
            const float G0 = fin[sq * 16 + 1], G1 = fin[sq * 16 + 2];
            const float G2 = fin[sq * 16 + 3], G3 = fin[sq * 16 + 4];
            const float h00 = fin[sq * 16 + 5],  h01 = fin[sq * 16 + 6];
            const float h02 = fin[sq * 16 + 7],  h03 = fin[sq * 16 + 8];
            const float h11 = fin[sq * 16 + 9],  h12 = fin[sq * 16 + 10];
            const float h13 = fin[sq * 16 + 11], h22 = fin[sq * 16 + 12];
            const float h23 = fin[sq * 16 + 13], h33 = fin[sq * 16 + 14];
            const float r  = coords[s * 4 + 1];
            const float th = coords[s * 4 + 2];
            const float sn = sinf(th), cs = cosf(th);
            const float E  = expf(f);
            const float r2 = r * r;
            const float gi1 = 1.f / E, gi2 = 1.f / r2, gi3 = 1.f / (r2 * sn * sn);

            auto GF = [&](int k) -> float {
                return k == 0 ? G0 : k == 1 ? G1 : k == 2 ? G2 : G3;
            };
            auto HS = [&](int k, int l) -> float {
                int a = k < l ? k : l, b = k < l ? l : k;
                return a == 0 ? (b == 0 ? h00 : b == 1 ? h01 : b == 2 ? h02 : h03)
                     : a == 1 ? (b == 1 ? h11 : b == 2 ? h12 : h13)
                     : a == 2 ? (b == 2 ? h22 : h23) : h33;
            };
            auto GI = [&](int a) -> float {
                return a == 0 ? -1.f : a == 1 ? gi1 : a == 2 ? gi2 : gi3;
            };
            auto dgv = [&](int a, int k) -> float {
                if (a == 1) return E * GF(k);
                if (a == 2) return k == 1 ? 2.f * r : 0.f;
                if (a == 3) {
                    if (k == 1) return 2.f * r * sn * sn;
                    if (k == 2) return 2.f * r2 * sn * cs;
                }
                return 0.f;
            };
            auto ddg = [&](int a, int k, int l) -> float {
                if (a == 1) return E * fmaf(GF(k), GF(l), HS(k, l));
                if (a == 2) return (k == 1 && l == 1) ? 2.f : 0.f;
                if (a == 3) {
                    if (k == 1 && l == 1) return 2.f * sn * sn;
                    if ((k == 1 && l == 2) || (k == 2 && l == 1))
                        return 4.f * r * sn * cs;
                    if (k == 2 && l == 2) return 2.f * r2 * (cs * cs - sn * sn);
                }
                return 0.f;
            };
            auto SYMF = [&](int a, int i, int jx) -> float {
                float sy = 0.f;
                if (a == i)  sy += dgv(a, jx);
                if (a == jx) sy += dgv(a, i);
                if (i == jx) sy -= dgv(i, a);
                return sy;
            };
            auto DF = [&](int a, int i, int jx, int k) -> float {
                float ds = 0.f;
                if (a == i)  ds += ddg(a, jx, k);
                if (a == jx) ds += ddg(a, i, k);
                if (i == jx) ds -= ddg(i, a, k);
                float ga = GI(a);
                return 0.5f * (ga * ds - ga * ga * dgv(a, k) * SYMF(a, i, jx));
            };
            auto GMf = [&](int a, int i, int jx) -> float {
                return 0.5f * GI(a) * SYMF(a, i, jx);
            };

            // ric[io][jo] (Ricci is symmetric)
            float ric = 0.f;
#pragma unroll
            for (int a = 0; a < 4; ++a) {
                ric += DF(a, jo, io, a) - DF(a, a, io, jo);
#pragma unroll
                for (int ee = 0; ee < 4; ++ee)
                    ric += GMf(a, a, ee) * GMf(ee, jo, io)
                         - GMf(a, jo, ee) * GMf(ee, a, io);
            }
            // Rs = sum_b gi[b] * ric[b][b] via 16-lane butterfly
            float contrib = (io == jo) ? GI(io) * ric : 0.f;
#pragma unroll
            for (int mask = 1; mask < 16; mask <<= 1)
                contrib += __shfl_xor(contrib, mask, 64);
            float v = GI(io) * GI(jo) * ric;
            if (io == jo) v -= 0.5f * GI(io) * contrib;
            out[s * 16 + e] = v;
        }
    }
}

extern "C" void kernel_launch(void* const* d_in, const int* in_sizes, int n_in,
                              void* d_out, int out_size, void* d_ws, size_t ws_size,
                              hipStream_t stream) {
    const float* coords = (const float*)d_in[0];
    const float* W1 = (const float*)d_in[1];
    const float* b1 = (const float*)d_in[2];
    const float* W2 = (const float*)d_in[3];
    const float* b2 = (const float*)d_in[4];
    const float* W3 = (const float*)d_in[5];
    const float* b3 = (const float*)d_in[6];
    const float* Wo = (const float*)d_in[7];
    const float* bo = (const float*)d_in[8];
    float* out = (float*)d_out;
    const int B = in_sizes[0] / 4;
    const int nblocks = (B + SPB - 1) / SPB;

    const size_t wt_bytes = (size_t)2 * HDIM * HDIM * sizeof(_Float16);
    if (ws_size >= wt_bytes) {
        _Float16* Wt = (_Float16*)d_ws;
        pack_wt<<<32, 1024, 0, stream>>>(W2, W3, Wt);
        mlp_fused<true><<<nblocks, 256, 0, stream>>>(
            coords, W1, b1, W2, b2, W3, b3, Wo, bo, Wt, out, B);
    } else {
        mlp_fused<false><<<nblocks, 256, 0, stream>>>(
            coords, W1, b1, W2, b2, W3, b3, Wo, bo, nullptr, out, B);
    }
}